// Round 1
// baseline (342.854 us; speedup 1.0000x reference)
//
#include <hip/hip_runtime.h>
#include <hip/hip_bf16.h>

typedef __bf16 bf16x8 __attribute__((ext_vector_type(8)));
typedef __bf16 bf16x4 __attribute__((ext_vector_type(4)));
typedef float  f32x4  __attribute__((ext_vector_type(4)));

#define K_DIM 1024
#define N_DIM 1024
#define BM 128
#define BN 128
#define BK 64

typedef unsigned int u32;
typedef u32 __attribute__((address_space(1))) u32_g;
typedef u32 __attribute__((address_space(3))) u32_s;

__device__ __forceinline__ void load16_lds(const void* g, void* s) {
    // async global->LDS, 16B per lane; LDS dest = wave-uniform base + lane*16
    __builtin_amdgcn_global_load_lds((u32_g*)g, (u32_s*)s, 16, 0, 0);
}

// ---------------- 1. global max|kernel| ----------------
__global__ void maxabs_kernel(const float* __restrict__ w, unsigned int* __restrict__ mx, int n4) {
    int i = blockIdx.x * blockDim.x + threadIdx.x;
    int stride = gridDim.x * blockDim.x;
    float m = 0.f;
    for (; i < n4; i += stride) {
        float4 v = ((const float4*)w)[i];
        m = fmaxf(m, fmaxf(fmaxf(fabsf(v.x), fabsf(v.y)), fmaxf(fabsf(v.z), fabsf(v.w))));
    }
#pragma unroll
    for (int off = 32; off > 0; off >>= 1)
        m = fmaxf(m, __shfl_down(m, off, 64));
    if ((threadIdx.x & 63) == 0) atomicMax(mx, __float_as_uint(m));
}

// ---------------- 2. W_eff^T (N x K, bf16) = quant-dequant(kernel) + a@b ----------------
__global__ void build_w_kernel(const float* __restrict__ kern, const float* __restrict__ amat,
                               const float* __restrict__ bmat, const unsigned int* __restrict__ mx,
                               __bf16* __restrict__ wt) {
    int t = blockIdx.x * blockDim.x + threadIdx.x;   // 0 .. 1M-1
    int k = t & (K_DIM - 1);
    int n = t >> 10;
    float scale = __uint_as_float(*mx) * (1.0f / 7.0f);
    float w = kern[k * N_DIM + n];
    float q = rintf(w / scale);                      // RNE == jnp.round
    q = fminf(fmaxf(q, -8.f), 7.f);
    float acc = q * scale;
#pragma unroll
    for (int r = 0; r < 16; ++r)
        acc += amat[k * 16 + r] * bmat[r * N_DIM + n];
    wt[(size_t)n * K_DIM + k] = (__bf16)acc;
}

// ---------------- 3. x fp32 -> bf16 ----------------
__global__ void cvt_x_kernel(const float4* __restrict__ x, bf16x4* __restrict__ xb, int n4) {
    int i = blockIdx.x * blockDim.x + threadIdx.x;
    if (i >= n4) return;
    float4 v = x[i];
    bf16x4 o;
    o.x = (__bf16)v.x; o.y = (__bf16)v.y; o.z = (__bf16)v.z; o.w = (__bf16)v.w;
    xb[i] = o;
}

// ---------------- 4. GEMM: out[M,N] = A[M,K] * Wt[N,K]^T + bias ----------------
// AMODE 0: A is preconverted bf16 (global_load_lds staging)
// AMODE 1: A is fp32 x, converted to bf16 during manual LDS staging
// LDS layout (both As and Bs): row-major [row][64 bf16], 16B chunk c of row r
// stored at physical chunk c ^ (r&7)  -> conflict-free ds_read_b128 later.
template <int AMODE>
__global__ __launch_bounds__(256, 2)
void gemm_kernel(const void* __restrict__ Ain, const __bf16* __restrict__ wt,
                 const float* __restrict__ bias, float* __restrict__ out) {
    __shared__ __attribute__((aligned(16))) __bf16 As[BM * BK];
    __shared__ __attribute__((aligned(16))) __bf16 Bs[BN * BK];

    const int tid  = threadIdx.x;
    const int lane = tid & 63;
    const int wave = tid >> 6;
    const int wm = (wave >> 1) * 64;
    const int wn = (wave & 1) * 64;
    const int bm0 = blockIdx.y * BM;
    const int bn0 = blockIdx.x * BN;
    const int l15 = lane & 15;
    const int l4  = lane >> 4;

    f32x4 acc[4][4] = {};

    // staging geometry: 64 lanes x 16B = 8 rows (128B each) per wave-issue
    const int srow = lane >> 3;           // row within the 8-row group
    const int gch  = (lane & 7) ^ srow;   // swizzled source chunk (row base % 8 == 0)

    for (int k0 = 0; k0 < K_DIM; k0 += BK) {
        __syncthreads();
        // ---- stage B tile (Wt rows = n), always bf16 via global_load_lds ----
#pragma unroll
        for (int i = 0; i < 4; ++i) {
            int r = i * 32 + wave * 8;    // wave-uniform base row
            const __bf16* g = wt + (size_t)(bn0 + r + srow) * K_DIM + k0 + gch * 8;
            load16_lds(g, &Bs[r * BK]);
        }
        // ---- stage A tile ----
        if (AMODE == 0) {
            const __bf16* xb = (const __bf16*)Ain;
#pragma unroll
            for (int i = 0; i < 4; ++i) {
                int r = i * 32 + wave * 8;
                const __bf16* g = xb + (size_t)(bm0 + r + srow) * K_DIM + k0 + gch * 8;
                load16_lds(g, &As[r * BK]);
            }
        } else {
            const float* x = (const float*)Ain;
#pragma unroll
            for (int j = 0; j < 8; ++j) {
                int f  = j * 256 + tid;   // float4 index within 128x64 tile
                int r  = f >> 4;
                int c4 = f & 15;          // 4-elem column group
                float4 v = *(const float4*)(x + (size_t)(bm0 + r) * K_DIM + k0 + c4 * 4);
                int p = (c4 >> 1) ^ (r & 7);
                bf16x4 o;
                o.x = (__bf16)v.x; o.y = (__bf16)v.y; o.z = (__bf16)v.z; o.w = (__bf16)v.w;
                *(bf16x4*)(&As[r * BK + p * 8 + (c4 & 1) * 4]) = o;
            }
        }
        __syncthreads();

        // ---- compute: 2 k-steps x 16 MFMA(16x16x32) per wave ----
#pragma unroll
        for (int ks = 0; ks < 2; ++ks) {
            bf16x8 af[4], bfr[4];
#pragma unroll
            for (int mt = 0; mt < 4; ++mt) {
                int r = wm + mt * 16 + l15;
                int p = (ks * 4 + l4) ^ (r & 7);
                af[mt] = *(const bf16x8*)(&As[r * BK + p * 8]);
            }
#pragma unroll
            for (int nt = 0; nt < 4; ++nt) {
                int r = wn + nt * 16 + l15;
                int p = (ks * 4 + l4) ^ (r & 7);
                bfr[nt] = *(const bf16x8*)(&Bs[r * BK + p * 8]);
            }
#pragma unroll
            for (int mt = 0; mt < 4; ++mt)
#pragma unroll
                for (int nt = 0; nt < 4; ++nt)
                    acc[mt][nt] = __builtin_amdgcn_mfma_f32_16x16x32_bf16(
                        af[mt], bfr[nt], acc[mt][nt], 0, 0, 0);
        }
    }

    // ---- epilogue: C/D layout col = lane&15, row = (lane>>4)*4 + reg ----
#pragma unroll
    for (int nt = 0; nt < 4; ++nt) {
        int n = bn0 + wn + nt * 16 + l15;
        float bv = bias[n];
#pragma unroll
        for (int mt = 0; mt < 4; ++mt) {
            int m = bm0 + wm + mt * 16 + l4 * 4;
            float* op = out + (size_t)m * N_DIM + n;
#pragma unroll
            for (int r = 0; r < 4; ++r)
                op[(size_t)r * N_DIM] = acc[mt][nt][r] + bv;
        }
    }
}

extern "C" void kernel_launch(void* const* d_in, const int* in_sizes, int n_in,
                              void* d_out, int out_size, void* d_ws, size_t ws_size,
                              hipStream_t stream) {
    const float* x    = (const float*)d_in[0];
    const float* kern = (const float*)d_in[1];
    const float* bias = (const float*)d_in[2];
    const float* amat = (const float*)d_in[3];
    const float* bmat = (const float*)d_in[4];
    float* out = (float*)d_out;
    const int M = in_sizes[0] / K_DIM;   // 32768

    unsigned int* mx = (unsigned int*)d_ws;
    __bf16* wt = (__bf16*)((char*)d_ws + 256);
    const size_t xb_off    = 256 + (size_t)N_DIM * K_DIM * sizeof(__bf16);
    const size_t need_fast = xb_off + (size_t)M * K_DIM * sizeof(__bf16);

    hipMemsetAsync(d_ws, 0, 4, stream);
    maxabs_kernel<<<256, 256, 0, stream>>>(kern, mx, K_DIM * N_DIM / 4);
    build_w_kernel<<<K_DIM * N_DIM / 256, 256, 0, stream>>>(kern, amat, bmat, mx, wt);

    dim3 grid(N_DIM / BN, M / BM);
    if (ws_size >= need_fast) {
        __bf16* xb = (__bf16*)((char*)d_ws + xb_off);
        int n4 = M * K_DIM / 4;
        cvt_x_kernel<<<(n4 + 255) / 256, 256, 0, stream>>>((const float4*)x, (bf16x4*)xb, n4);
        gemm_kernel<0><<<grid, 256, 0, stream>>>(xb, wt, bias, out);
    } else {
        gemm_kernel<1><<<grid, 256, 0, stream>>>(x, wt, bias, out);
    }
}

// Round 2
// 305.974 us; speedup vs baseline: 1.1205x; 1.1205x over previous
//
#include <hip/hip_runtime.h>
#include <hip/hip_bf16.h>

typedef __bf16 bf16x8 __attribute__((ext_vector_type(8)));
typedef __bf16 bf16x4 __attribute__((ext_vector_type(4)));
typedef float  f32x4  __attribute__((ext_vector_type(4)));

#define K_DIM 1024
#define N_DIM 1024
#define BM 128
#define BN 128
#define BK 64

typedef unsigned int u32;
typedef u32 __attribute__((address_space(1))) u32_g;
typedef u32 __attribute__((address_space(3))) u32_s;

__device__ __forceinline__ void load16_lds(const void* g, void* s) {
    // async global->LDS, 16B per lane; LDS dest = wave-uniform base + lane*16
    __builtin_amdgcn_global_load_lds((u32_g*)g, (u32_s*)s, 16, 0, 0);
}

// ---------------- 1. per-block max|kernel| (no atomics, no memset) ----------------
__global__ void maxabs_kernel(const float* __restrict__ w, float* __restrict__ blockmax, int n4) {
    __shared__ float sm[4];
    int i = blockIdx.x * blockDim.x + threadIdx.x;
    int stride = gridDim.x * blockDim.x;
    float m = 0.f;
    for (; i < n4; i += stride) {
        float4 v = ((const float4*)w)[i];
        m = fmaxf(m, fmaxf(fmaxf(fabsf(v.x), fabsf(v.y)), fmaxf(fabsf(v.z), fabsf(v.w))));
    }
#pragma unroll
    for (int off = 32; off > 0; off >>= 1)
        m = fmaxf(m, __shfl_down(m, off, 64));
    int lane = threadIdx.x & 63, wave = threadIdx.x >> 6;
    if (lane == 0) sm[wave] = m;
    __syncthreads();
    if (threadIdx.x == 0)
        blockmax[blockIdx.x] = fmaxf(fmaxf(sm[0], sm[1]), fmaxf(sm[2], sm[3]));
}

// ---------------- 2. W_eff^T (N x K, bf16) = quant-dequant(kernel) + a@b ----------------
__global__ void build_w_kernel(const float* __restrict__ kern, const float* __restrict__ amat,
                               const float* __restrict__ bmat, const float* __restrict__ blockmax,
                               __bf16* __restrict__ wt) {
    __shared__ float smax;
    if (threadIdx.x < 64) {
        float m = 0.f;
#pragma unroll
        for (int j = 0; j < 4; ++j) m = fmaxf(m, blockmax[threadIdx.x + j * 64]);
#pragma unroll
        for (int off = 32; off > 0; off >>= 1)
            m = fmaxf(m, __shfl_down(m, off, 64));
        if (threadIdx.x == 0) smax = m;
    }
    __syncthreads();
    float scale = smax * (1.0f / 7.0f);

    int t = blockIdx.x * blockDim.x + threadIdx.x;   // 0 .. 1M-1
    int k = t & (K_DIM - 1);
    int n = t >> 10;
    float w = kern[k * N_DIM + n];
    float q = rintf(w / scale);                      // RNE == jnp.round
    q = fminf(fmaxf(q, -8.f), 7.f);
    float acc = q * scale;
#pragma unroll
    for (int r = 0; r < 16; ++r)
        acc += amat[k * 16 + r] * bmat[r * N_DIM + n];
    wt[(size_t)n * K_DIM + k] = (__bf16)acc;
}

// ---------------- 3. x fp32 -> bf16 ----------------
__global__ void cvt_x_kernel(const float4* __restrict__ x, bf16x8* __restrict__ xb, int n8) {
    int i = blockIdx.x * blockDim.x + threadIdx.x;
    if (i >= n8) return;
    float4 v0 = x[i * 2];
    float4 v1 = x[i * 2 + 1];
    bf16x8 o;
    o[0] = (__bf16)v0.x; o[1] = (__bf16)v0.y; o[2] = (__bf16)v0.z; o[3] = (__bf16)v0.w;
    o[4] = (__bf16)v1.x; o[5] = (__bf16)v1.y; o[6] = (__bf16)v1.z; o[7] = (__bf16)v1.w;
    xb[i] = o;
}

// ---------------- 4. GEMM: out[M,N] = A[M,K] * Wt[N,K]^T + bias ----------------
// Linear grid with XCD-aware swizzle: all 8 N-tiles of one M-panel land on the
// SAME XCD (consecutive linear block ids round-robin XCDs), so the x panel is
// fetched into that XCD's L2 once and reused 8x.
// LDS layout (As and Bs): row-major [row][64 bf16], 16B chunk c of row r stored
// at physical chunk c ^ (r&7) -> conflict-free ds_read_b128.
template <int AMODE>
__global__ __launch_bounds__(256, 4)
void gemm_kernel(const void* __restrict__ Ain, const __bf16* __restrict__ wt,
                 const float* __restrict__ bias, float* __restrict__ out) {
    __shared__ __attribute__((aligned(16))) __bf16 As[BM * BK];
    __shared__ __attribute__((aligned(16))) __bf16 Bs[BN * BK];

    const int tid  = threadIdx.x;
    const int lane = tid & 63;
    const int wave = tid >> 6;
    const int wm = (wave >> 1) * 64;
    const int wn = (wave & 1) * 64;

    // swizzle: l%8 = xcd; i=l/8; n_tile = i%8; m_panel = (i/8)*8 + l%8
    const int l = blockIdx.x;
    const int i = l >> 3;
    const int bn0 = (i & 7) * BN;
    const int bm0 = (((i >> 3) << 3) | (l & 7)) * BM;

    const int l15 = lane & 15;
    const int l4  = lane >> 4;

    f32x4 acc[4][4] = {};

    // staging geometry: 64 lanes x 16B = 8 rows (128B each) per wave-issue
    const int srow = lane >> 3;           // row within the 8-row group
    const int gch  = (lane & 7) ^ srow;   // swizzled source chunk

    for (int k0 = 0; k0 < K_DIM; k0 += BK) {
        __syncthreads();
        // ---- stage B tile (Wt rows = n) ----
#pragma unroll
        for (int j = 0; j < 4; ++j) {
            int r = j * 32 + wave * 8;    // wave-uniform base row
            const __bf16* g = wt + (size_t)(bn0 + r + srow) * K_DIM + k0 + gch * 8;
            load16_lds(g, &Bs[r * BK]);
        }
        // ---- stage A tile ----
        if (AMODE == 0) {
            const __bf16* xb = (const __bf16*)Ain;
#pragma unroll
            for (int j = 0; j < 4; ++j) {
                int r = j * 32 + wave * 8;
                const __bf16* g = xb + (size_t)(bm0 + r + srow) * K_DIM + k0 + gch * 8;
                load16_lds(g, &As[r * BK]);
            }
        } else {
            const float* x = (const float*)Ain;
#pragma unroll
            for (int j = 0; j < 8; ++j) {
                int f  = j * 256 + tid;   // float4 index within 128x64 tile
                int r  = f >> 4;
                int c4 = f & 15;
                float4 v = *(const float4*)(x + (size_t)(bm0 + r) * K_DIM + k0 + c4 * 4);
                int p = (c4 >> 1) ^ (r & 7);
                bf16x4 o;
                o.x = (__bf16)v.x; o.y = (__bf16)v.y; o.z = (__bf16)v.z; o.w = (__bf16)v.w;
                *(bf16x4*)(&As[r * BK + p * 8 + (c4 & 1) * 4]) = o;
            }
        }
        __syncthreads();

        // ---- compute: 2 k-steps x 16 MFMA(16x16x32) per wave ----
#pragma unroll
        for (int ks = 0; ks < 2; ++ks) {
            bf16x8 af[4], bfr[4];
#pragma unroll
            for (int mt = 0; mt < 4; ++mt) {
                int r = wm + mt * 16 + l15;
                int p = (ks * 4 + l4) ^ (r & 7);
                af[mt] = *(const bf16x8*)(&As[r * BK + p * 8]);
            }
#pragma unroll
            for (int nt = 0; nt < 4; ++nt) {
                int r = wn + nt * 16 + l15;
                int p = (ks * 4 + l4) ^ (r & 7);
                bfr[nt] = *(const bf16x8*)(&Bs[r * BK + p * 8]);
            }
#pragma unroll
            for (int mt = 0; mt < 4; ++mt)
#pragma unroll
                for (int nt = 0; nt < 4; ++nt)
                    acc[mt][nt] = __builtin_amdgcn_mfma_f32_16x16x32_bf16(
                        af[mt], bfr[nt], acc[mt][nt], 0, 0, 0);
        }
    }

    // ---- epilogue: C/D layout col = lane&15, row = (lane>>4)*4 + reg ----
#pragma unroll
    for (int nt = 0; nt < 4; ++nt) {
        int n = bn0 + wn + nt * 16 + l15;
        float bv = bias[n];
#pragma unroll
        for (int mt = 0; mt < 4; ++mt) {
            int m = bm0 + wm + mt * 16 + l4 * 4;
            float* op = out + (size_t)m * N_DIM + n;
#pragma unroll
            for (int r = 0; r < 4; ++r)
                op[(size_t)r * N_DIM] = acc[mt][nt][r] + bv;
        }
    }
}

extern "C" void kernel_launch(void* const* d_in, const int* in_sizes, int n_in,
                              void* d_out, int out_size, void* d_ws, size_t ws_size,
                              hipStream_t stream) {
    const float* x    = (const float*)d_in[0];
    const float* kern = (const float*)d_in[1];
    const float* bias = (const float*)d_in[2];
    const float* amat = (const float*)d_in[3];
    const float* bmat = (const float*)d_in[4];
    float* out = (float*)d_out;
    const int M = in_sizes[0] / K_DIM;   // 32768

    float* blockmax = (float*)d_ws;                          // 256 floats
    __bf16* wt = (__bf16*)((char*)d_ws + 4096);
    const size_t xb_off    = 4096 + (size_t)N_DIM * K_DIM * sizeof(__bf16);
    const size_t need_fast = xb_off + (size_t)M * K_DIM * sizeof(__bf16);

    maxabs_kernel<<<256, 256, 0, stream>>>(kern, blockmax, K_DIM * N_DIM / 4);
    build_w_kernel<<<K_DIM * N_DIM / 256, 256, 0, stream>>>(kern, amat, bmat, blockmax, wt);

    const int nblocks = (M / BM) * (N_DIM / BN);
    if (ws_size >= need_fast) {
        __bf16* xb = (__bf16*)((char*)d_ws + xb_off);
        int n8 = M * K_DIM / 8;
        cvt_x_kernel<<<(n8 + 255) / 256, 256, 0, stream>>>((const float4*)x, (bf16x8*)xb, n8);
        gemm_kernel<0><<<nblocks, 256, 0, stream>>>(xb, wt, bias, out);
    } else {
        gemm_kernel<1><<<nblocks, 256, 0, stream>>>(x, wt, bias, out);
    }
}